// Round 1
// baseline (166.344 us; speedup 1.0000x reference)
//
#include <hip/hip_runtime.h>

#define SCAN_THREADS 256
#define EPT 8
#define CHUNK (SCAN_THREADS * EPT)   // 2048 elements per scan block

// ---------------------------------------------------------------------------
// K1: filtered = residues * sigmoid(attrs @ w + b); scatter +/- into delta.
// tpre/tpost together form a permutation of [0, 2N) -> every slot written once.
__global__ void k1_filter_scatter(const float* __restrict__ attrs,
                                  const float* __restrict__ weight,
                                  const float* __restrict__ bias,
                                  const float* __restrict__ residues,
                                  const int* __restrict__ tpre,
                                  const int* __restrict__ tpost,
                                  float* __restrict__ delta,
                                  int N) {
    int u = blockIdx.x * blockDim.x + threadIdx.x;
    if (u >= N) return;
    const float4* a4 = (const float4*)(attrs + (size_t)u * 8);
    float4 a0 = a4[0];
    float4 a1 = a4[1];
    float4 w0 = ((const float4*)weight)[0];
    float4 w1 = ((const float4*)weight)[1];
    float logit = a0.x * w0.x + a0.y * w0.y + a0.z * w0.z + a0.w * w0.w +
                  a1.x * w1.x + a1.y * w1.y + a1.z * w1.z + a1.w * w1.w +
                  bias[0];
    float sig = 1.0f / (1.0f + __expf(-logit));
    float f = residues[u] * sig;
    delta[tpre[u]]  =  f;
    delta[tpost[u]] = -f;
}

// ---------------------------------------------------------------------------
// K2: per-chunk partial sums.
__global__ void k2_partials(const float* __restrict__ delta,
                            float* __restrict__ partials, int T) {
    __shared__ float sdata[SCAN_THREADS / 64];
    int base = blockIdx.x * CHUNK + threadIdx.x * EPT;
    float s = 0.0f;
    if (base + EPT <= T) {
        float4 v0 = *(const float4*)(delta + base);
        float4 v1 = *(const float4*)(delta + base + 4);
        s = v0.x + v0.y + v0.z + v0.w + v1.x + v1.y + v1.z + v1.w;
    } else {
        for (int i = 0; i < EPT; ++i)
            if (base + i < T) s += delta[base + i];
    }
    for (int d = 32; d > 0; d >>= 1) s += __shfl_down(s, d, 64);
    int lane = threadIdx.x & 63, wid = threadIdx.x >> 6;
    if (lane == 0) sdata[wid] = s;
    __syncthreads();
    if (threadIdx.x == 0) {
        float tot = 0.0f;
        for (int i = 0; i < SCAN_THREADS / 64; ++i) tot += sdata[i];
        partials[blockIdx.x] = tot;
    }
}

// ---------------------------------------------------------------------------
// K3: single-wave exclusive scan of chunk partials -> chunk offsets.
__global__ void k3_scan_partials(const float* __restrict__ partials,
                                 float* __restrict__ offsets, int numChunks) {
    int lane = threadIdx.x;          // launched with 64 threads
    int ppl = (numChunks + 63) >> 6; // partials per lane
    float s = 0.0f;
    for (int i = 0; i < ppl; ++i) {
        int idx = lane * ppl + i;
        if (idx < numChunks) s += partials[idx];
    }
    float x = s;
    for (int d = 1; d < 64; d <<= 1) {
        float y = __shfl_up(x, d, 64);
        if (lane >= d) x += y;
    }
    float run = x - s; // exclusive prefix of this lane's segment
    for (int i = 0; i < ppl; ++i) {
        int idx = lane * ppl + i;
        if (idx < numChunks) { offsets[idx] = run; run += partials[idx]; }
    }
}

// ---------------------------------------------------------------------------
// K4: in-place inclusive scan of each chunk + chunk offset.
__global__ void k4_scan_chunks(float* __restrict__ data,
                               const float* __restrict__ offsets, int T) {
    __shared__ float wavesums[SCAN_THREADS / 64];
    int base = blockIdx.x * CHUNK + threadIdx.x * EPT;
    float v[EPT];
    bool full = (base + EPT <= T);
    if (full) {
        float4 v0 = *(const float4*)(data + base);
        float4 v1 = *(const float4*)(data + base + 4);
        v[0] = v0.x; v[1] = v0.y; v[2] = v0.z; v[3] = v0.w;
        v[4] = v1.x; v[5] = v1.y; v[6] = v1.z; v[7] = v1.w;
    } else {
        for (int i = 0; i < EPT; ++i)
            v[i] = (base + i < T) ? data[base + i] : 0.0f;
    }
    float run = 0.0f;
    for (int i = 0; i < EPT; ++i) { run += v[i]; v[i] = run; }
    float tot = run;
    int lane = threadIdx.x & 63, wid = threadIdx.x >> 6;
    float x = tot;
    for (int d = 1; d < 64; d <<= 1) {
        float y = __shfl_up(x, d, 64);
        if (lane >= d) x += y;
    }
    if (lane == 63) wavesums[wid] = x;
    __syncthreads();
    float woff = 0.0f;
    for (int i = 0; i < wid; ++i) woff += wavesums[i];
    float add = (x - tot) + woff + offsets[blockIdx.x];
    if (full) {
        float4 o0 = make_float4(v[0] + add, v[1] + add, v[2] + add, v[3] + add);
        float4 o1 = make_float4(v[4] + add, v[5] + add, v[6] + add, v[7] + add);
        *(float4*)(data + base)     = o0;
        *(float4*)(data + base + 4) = o1;
    } else {
        for (int i = 0; i < EPT; ++i)
            if (base + i < T) data[base + i] = v[i] + add;
    }
}

// ---------------------------------------------------------------------------
// K5: per-node value v[u] = ycum[tpre[u]].
__global__ void k5_node_values(const float* __restrict__ ycum,
                               const int* __restrict__ tpre,
                               float* __restrict__ vnode, int N) {
    int u = blockIdx.x * blockDim.x + threadIdx.x;
    if (u < N) vnode[u] = ycum[tpre[u]];
}

// ---------------------------------------------------------------------------
// K6: per-pixel gather, vectorized x4.
__global__ void k6_gather(const float* __restrict__ vnode,
                          const int* __restrict__ nop,
                          float* __restrict__ out, int P) {
    int i = (blockIdx.x * blockDim.x + threadIdx.x) * 4;
    if (i + 4 <= P) {
        int4 n = *(const int4*)(nop + i);
        float4 o = make_float4(vnode[n.x], vnode[n.y], vnode[n.z], vnode[n.w]);
        *(float4*)(out + i) = o;
    } else {
        for (; i < P; ++i) out[i] = vnode[nop[i]];
    }
}

// K6 fallback: direct double gather (no vnode scratch needed).
__global__ void k6_direct(const float* __restrict__ ycum,
                          const int* __restrict__ tpre,
                          const int* __restrict__ nop,
                          float* __restrict__ out, int P) {
    int i = (blockIdx.x * blockDim.x + threadIdx.x) * 4;
    if (i + 4 <= P) {
        int4 n = *(const int4*)(nop + i);
        float4 o = make_float4(ycum[tpre[n.x]], ycum[tpre[n.y]],
                               ycum[tpre[n.z]], ycum[tpre[n.w]]);
        *(float4*)(out + i) = o;
    } else {
        for (; i < P; ++i) out[i] = ycum[tpre[nop[i]]];
    }
}

extern "C" void kernel_launch(void* const* d_in, const int* in_sizes, int n_in,
                              void* d_out, int out_size, void* d_ws, size_t ws_size,
                              hipStream_t stream) {
    const float* weight   = (const float*)d_in[0];
    const float* bias     = (const float*)d_in[1];
    const float* residues = (const float*)d_in[2];
    const float* attrs    = (const float*)d_in[3];
    const int*   tpre     = (const int*)d_in[4];
    const int*   tpost    = (const int*)d_in[5];
    const int*   nop      = (const int*)d_in[6];
    float* out = (float*)d_out;

    const int N = in_sizes[2];        // 500,000
    const int T = 2 * N;              // 1,000,000
    const int P = out_size;           // 8,388,608
    const int numChunks = (T + CHUNK - 1) / CHUNK;   // 489

    // Workspace layout tiers (harness poisons ws with 0xAA; we write before read).
    size_t needFull = (size_t)(T + N + 2 * 1024) * sizeof(float);
    size_t needMid  = (size_t)(N + 2 * 1024) * sizeof(float);

    float* delta;
    float* vnode    = nullptr;
    float* partials;
    float* offsets;
    bool useVnode = true;

    if (ws_size >= needFull) {
        delta    = (float*)d_ws;
        vnode    = delta + T;
        partials = vnode + N;
        offsets  = partials + 1024;
    } else if (ws_size >= needMid) {
        delta    = out;               // out is dead until K6 rewrites it fully
        vnode    = (float*)d_ws;
        partials = vnode + N;
        offsets  = partials + 1024;
    } else {
        delta    = out;
        partials = (float*)d_ws;
        offsets  = partials + 1024;
        useVnode = false;
    }

    k1_filter_scatter<<<(N + 255) / 256, 256, 0, stream>>>(
        attrs, weight, bias, residues, tpre, tpost, delta, N);
    k2_partials<<<numChunks, SCAN_THREADS, 0, stream>>>(delta, partials, T);
    k3_scan_partials<<<1, 64, 0, stream>>>(partials, offsets, numChunks);
    k4_scan_chunks<<<numChunks, SCAN_THREADS, 0, stream>>>(delta, offsets, T);

    int gatherBlocks = (P / 4 + 255) / 256;
    if (useVnode) {
        k5_node_values<<<(N + 255) / 256, 256, 0, stream>>>(delta, tpre, vnode, N);
        k6_gather<<<gatherBlocks, 256, 0, stream>>>(vnode, nop, out, P);
    } else {
        k6_direct<<<gatherBlocks, 256, 0, stream>>>(delta, tpre, nop, out, P);
    }
}